// Round 5
// baseline (180.335 us; speedup 1.0000x reference)
//
#include <hip/hip_runtime.h>
#include <math.h>

#define HH 64
#define WW 64
#define CIN 256
#define COUT 256
#define KKT 9
#define HWSZ 4096
#define VP 260                 // LDS row pitch in shorts

typedef __bf16  v8bf   __attribute__((ext_vector_type(8)));
typedef float   v4f    __attribute__((ext_vector_type(4)));
typedef short   short8 __attribute__((ext_vector_type(8)));
typedef unsigned short ushort4v __attribute__((ext_vector_type(4)));

__device__ inline unsigned short f2bf(float f) {   // RNE
    union { float f; unsigned u; } uf; uf.f = f;
    unsigned r = uf.u + 0x7fff + ((uf.u >> 16) & 1);
    return (unsigned short)(r >> 16);
}
__device__ inline float bf2f(unsigned short u) {
    union { unsigned u; float f; } uf; uf.u = ((unsigned)u) << 16;
    return uf.f;
}

// ---------------------------------------------------------------------------
// Merged prep kernel. Blocks 0..255: x -> x_t (channel-last bf16).
// Blocks 256..511: w -> wprep (LDS-staged, coalesced 16B writes).
// Blocks 512..583: w_off -> woffp.
// ---------------------------------------------------------------------------
__global__ __launch_bounds__(256) void k_prep(const float* __restrict__ x,
                                              const float* __restrict__ w,
                                              const float* __restrict__ w_off,
                                              unsigned short* __restrict__ x_t,
                                              unsigned short* __restrict__ wprep,
                                              unsigned short* __restrict__ woffp) {
    __shared__ float s_w[2304];
    int id  = blockIdx.x;
    int tid = threadIdx.x;
    if (id < 256) {
        int b  = id >> 6;
        int h  = id & 63;
        int px  = tid & 63;
        int oct = tid >> 6;
        const float* xr = x + (((size_t)b * CIN) * HH + h) * WW;
        unsigned short* orow = x_t + (((size_t)id) * WW + px) * CIN;
        for (int g = 0; g < 8; g++) {
            int cb = g * 32 + oct * 8;
            unsigned short v[8];
#pragma unroll
            for (int j = 0; j < 8; j++)
                v[j] = f2bf(xr[(size_t)(cb + j) * HWSZ + px]);
            *(short8*)(orow + cb) = *(short8*)v;
        }
    } else if (id < 512) {
        int o = id - 256;
        for (int i = tid; i < 2304; i += 256) s_w[i] = w[(size_t)o * 2304 + i];
        __syncthreads();
        // 576 ushort4 units: u -> (t = u>>3, kq = u&7)
        for (int u = tid; u < 576; u += 256) {
            int t  = u >> 3;
            int kq = u & 7;
            unsigned short v[4];
#pragma unroll
            for (int j = 0; j < 4; j++) {
                int kp = t * 32 + kq * 4 + j;
                int kk = kp >> 8;
                int c  = kp & 255;
                v[j] = f2bf(s_w[c * 9 + kk]);
            }
            *(ushort4v*)&wprep[((size_t)(t * 256 + o)) * 32 + kq * 4] = *(ushort4v*)v;
        }
    } else {
        int t = id - 512;              // 0..71
#pragma unroll
        for (int i = 0; i < 4; i++) {
            int idx = i * 256 + tid;
            int och = idx >> 5;
            int ki  = idx & 31;
            int kp  = t * 32 + ki;
            int kk  = kp >> 8;
            int c   = kp & 255;
            float v = (och < 27) ? w_off[((size_t)och * 256 + c) * 9 + kk] : 0.f;
            woffp[(size_t)t * 1024 + idx] = f2bf(v);
        }
    }
}

// ---------------------------------------------------------------------------
// Offset conv MFMA. Grid 512: block = (b, h, px-half of 32). 256 thr, 4 waves.
// Stage 3 rows x 34 px once (1 barrier), K-chunks split over wave-pairs,
// LDS reduce. 3 barriers total, 2 blocks/CU.
// ---------------------------------------------------------------------------
__global__ __launch_bounds__(256) void k_off_mfma(const unsigned short* __restrict__ x_t,
                                                  const unsigned short* __restrict__ woffp,
                                                  const float* __restrict__ b_off,
                                                  float* __restrict__ om) {
    int id    = blockIdx.x;
    int g     = id & 7;
    int phalf = (id >> 3) & 1;
    int hi    = (id >> 4) & 7;
    int b     = id >> 7;
    int h     = g * 8 + hi;
    int p0    = phalf * 32;
    int tid  = threadIdx.x;
    int lane = tid & 63;
    int wv   = tid >> 6;               // 0..3
    int g2   = wv >> 1;                // K-split group
    int ntw  = wv & 1;                 // px 16-tile
    int m16  = lane & 15;
    int quad = lane >> 4;

    __shared__ unsigned short s_row[3 * 34 * VP];   // 53 KB
    __shared__ float s_red[2][32][33];

    const unsigned short* xb = x_t + (size_t)b * HWSZ * CIN;

    // stage rows h-1..h+1, px p0-1..p0+32 (34 cols), zero outside
    for (int u = tid; u < 3 * 1088; u += 256) {     // short8 units
        int row = u / 1088;
        int rem = u - row * 1088;
        int px  = rem >> 5;
        int c8  = (rem & 31) * 8;
        int y   = h + row - 1;
        int xg  = p0 + px - 1;
        short8 val = (short8)0;
        if ((unsigned)y < HH && (unsigned)xg < WW)
            val = *(const short8*)(xb + ((size_t)y * WW + xg) * CIN + c8);
        *(short8*)&s_row[(row * 34 + px) * VP + c8] = val;
    }
    __syncthreads();

    v4f acc[2];
    acc[0] = (v4f)(0.f);
    acc[1] = (v4f)(0.f);

#pragma unroll
    for (int ky = 0; ky < 3; ky++) {
#pragma unroll
        for (int kx = 0; kx < 3; kx++) {
#pragma unroll
            for (int c2 = 0; c2 < 4; c2++) {
                int ch = c2 * 2 + g2;
                int t  = (ky * 3 + kx) * 8 + ch;
                const unsigned short* wp = woffp + (size_t)t * 1024;
                short8 af0 = *(const short8*)(wp + m16 * 32 + quad * 8);
                short8 af1 = *(const short8*)(wp + (16 + m16) * 32 + quad * 8);
                short8 bfr = *(const short8*)
                    &s_row[(ky * 34 + ntw * 16 + m16 + kx) * VP + ch * 32 + quad * 8];
                acc[0] = __builtin_amdgcn_mfma_f32_16x16x32_bf16(
                    __builtin_bit_cast(v8bf, af0), __builtin_bit_cast(v8bf, bfr), acc[0], 0, 0, 0);
                acc[1] = __builtin_amdgcn_mfma_f32_16x16x32_bf16(
                    __builtin_bit_cast(v8bf, af1), __builtin_bit_cast(v8bf, bfr), acc[1], 0, 0, 0);
            }
        }
    }

#pragma unroll
    for (int mt = 0; mt < 2; mt++)
#pragma unroll
        for (int r = 0; r < 4; r++)
            s_red[g2][mt * 16 + quad * 4 + r][ntw * 16 + m16] = acc[mt][r];
    __syncthreads();

    for (int i2 = tid; i2 < 27 * 32; i2 += 256) {
        int och = i2 >> 5;
        int px  = i2 & 31;
        float s = s_red[0][och][px] + s_red[1][och][px] + b_off[och];
        om[((size_t)b * 27 + och) * HWSZ + h * WW + p0 + px] = s;
    }
}

// ---------------------------------------------------------------------------
// Main fused kernel: 512 thr, tile 256o x 64px, double-buffered s_v,
// V-gathers for kk+1 issued before MFMA(kk), W-frags prefetched 1 chunk ahead.
// ---------------------------------------------------------------------------
__global__ __launch_bounds__(512, 2) void k_main(const unsigned short* __restrict__ x_t,
                                                 const float* __restrict__ om,
                                                 const unsigned short* __restrict__ wprep,
                                                 float* __restrict__ out) {
    int id = blockIdx.x;
    int g  = id & 7, hi = (id >> 3) & 7, b = id >> 6;
    int h  = g * 8 + hi;
    int tid  = threadIdx.x;
    int lane = tid & 63;
    int oct  = tid >> 6;
    int m16  = lane & 15;
    int quad = lane >> 4;

    __shared__ int4   s_base[KKT][64];
    __shared__ float4 s_wt  [KKT][64];
    __shared__ unsigned short s_v[2][64 * VP];

    // ---- Phase A: sampling params ----
    const float* omb = om + (size_t)b * 27 * HWSZ + h * WW;
    for (int i = tid; i < KKT * 64; i += 512) {
        int kk = i >> 6;
        int p  = i & 63;
        float offy = omb[(size_t)(2 * kk)     * HWSZ + p];
        float offx = omb[(size_t)(2 * kk + 1) * HWSZ + p];
        float mv   = omb[(size_t)(18 + kk)    * HWSZ + p];
        int ky = kk / 3, kx = kk - 3 * (kk / 3);
        float py = (float)(h - 1 + ky) + offy;
        float px = (float)(p - 1 + kx) + offx;
        float y0f = floorf(py);
        float x0f = floorf(px);
        float ly = py - y0f, lx = px - x0f;
        int y0 = (int)y0f, x0 = (int)x0f;
        float m = 1.f / (1.f + __expf(-mv));
        bool yv0 = (unsigned)y0       < HH;
        bool yv1 = (unsigned)(y0 + 1) < HH;
        bool xv0 = (unsigned)x0       < WW;
        bool xv1 = (unsigned)(x0 + 1) < WW;
        int y0c = min(max(y0, 0), HH - 1);
        int y1c = min(max(y0 + 1, 0), HH - 1);
        int x0c = min(max(x0, 0), WW - 1);
        int x1c = min(max(x0 + 1, 0), WW - 1);
        s_base[kk][p] = make_int4((y0c * WW + x0c) * CIN, (y0c * WW + x1c) * CIN,
                                  (y1c * WW + x0c) * CIN, (y1c * WW + x1c) * CIN);
        s_wt[kk][p] = make_float4(
            (yv0 && xv0) ? (1.f - ly) * (1.f - lx) * m : 0.f,
            (yv0 && xv1) ? (1.f - ly) * lx         * m : 0.f,
            (yv1 && xv0) ? ly * (1.f - lx)         * m : 0.f,
            (yv1 && xv1) ? ly * lx                 * m : 0.f);
    }
    __syncthreads();

    v4f acc[2][4];
#pragma unroll
    for (int mt = 0; mt < 2; mt++)
#pragma unroll
        for (int nt = 0; nt < 4; nt++) acc[mt][nt] = (v4f)(0.f);

    const unsigned short* xb = x_t + (size_t)b * HWSZ * CIN;
    const unsigned short* xc = xb + lane * 4;

    ushort4v vt[8][4];
    // prefetch V gathers for kk=0 (coalesced: lanes span channels)
#pragma unroll
    for (int i = 0; i < 8; i++) {
        int4 bp = s_base[0][oct * 8 + i];
        vt[i][0] = *(const ushort4v*)(xc + bp.x);
        vt[i][1] = *(const ushort4v*)(xc + bp.y);
        vt[i][2] = *(const ushort4v*)(xc + bp.z);
        vt[i][3] = *(const ushort4v*)(xc + bp.w);
    }

    for (int kk = 0; kk < KKT; kk++) {
        unsigned short* vbuf = s_v[kk & 1];

        // ---- convert + store V(kk) ----
#pragma unroll
        for (int i = 0; i < 8; i++) {
            int px = oct * 8 + i;
            float4 wt = s_wt[kk][px];
            unsigned short vv[4];
#pragma unroll
            for (int j = 0; j < 4; j++) {
                float val = wt.x * bf2f(vt[i][0][j]) + wt.y * bf2f(vt[i][1][j])
                          + wt.z * bf2f(vt[i][2][j]) + wt.w * bf2f(vt[i][3][j]);
                vv[j] = f2bf(val);
            }
            *(ushort4v*)&vbuf[px * VP + lane * 4] = *(ushort4v*)vv;
        }
        __syncthreads();

        // ---- issue V gathers for kk+1 (in flight during MFMA) ----
        if (kk < KKT - 1) {
#pragma unroll
            for (int i = 0; i < 8; i++) {
                int4 bp = s_base[kk + 1][oct * 8 + i];
                vt[i][0] = *(const ushort4v*)(xc + bp.x);
                vt[i][1] = *(const ushort4v*)(xc + bp.y);
                vt[i][2] = *(const ushort4v*)(xc + bp.z);
                vt[i][3] = *(const ushort4v*)(xc + bp.w);
            }
        }

        // ---- MFMA phase: 8 chunks, W prefetched one ahead ----
        int t0 = kk * 8;
        const unsigned short* wp = wprep + ((size_t)t0 * 256 + oct * 32) * 32;
        short8 wa0 = *(const short8*)(wp + m16 * 32 + quad * 8);
        short8 wa1 = *(const short8*)(wp + (16 + m16) * 32 + quad * 8);
#pragma unroll
        for (int ch = 0; ch < 8; ch++) {
            int tn = t0 + ch + 1;
            if (tn > 71) tn = 71;
            const unsigned short* wpn = wprep + ((size_t)tn * 256 + oct * 32) * 32;
            short8 wn0 = *(const short8*)(wpn + m16 * 32 + quad * 8);
            short8 wn1 = *(const short8*)(wpn + (16 + m16) * 32 + quad * 8);
            short8 bfr[4];
#pragma unroll
            for (int nt = 0; nt < 4; nt++)
                bfr[nt] = *(const short8*)&vbuf[(nt * 16 + m16) * VP + ch * 32 + quad * 8];
#pragma unroll
            for (int nt = 0; nt < 4; nt++) {
                acc[0][nt] = __builtin_amdgcn_mfma_f32_16x16x32_bf16(
                    __builtin_bit_cast(v8bf, wa0), __builtin_bit_cast(v8bf, bfr[nt]),
                    acc[0][nt], 0, 0, 0);
                acc[1][nt] = __builtin_amdgcn_mfma_f32_16x16x32_bf16(
                    __builtin_bit_cast(v8bf, wa1), __builtin_bit_cast(v8bf, bfr[nt]),
                    acc[1][nt], 0, 0, 0);
            }
            wa0 = wn0;
            wa1 = wn1;
        }
    }

    // ---- epilogue ----
    float* ob = out + ((size_t)b * COUT) * HWSZ + h * WW;
#pragma unroll
    for (int mt = 0; mt < 2; mt++)
#pragma unroll
        for (int nt = 0; nt < 4; nt++)
#pragma unroll
            for (int r = 0; r < 4; r++) {
                int o = oct * 32 + mt * 16 + quad * 4 + r;
                ob[(size_t)o * HWSZ + nt * 16 + m16] = acc[mt][nt][r];
            }
}

extern "C" void kernel_launch(void* const* d_in, const int* in_sizes, int n_in,
                              void* d_out, int out_size, void* d_ws, size_t ws_size,
                              hipStream_t stream) {
    const float* x     = (const float*)d_in[0];
    const float* w_off = (const float*)d_in[1];
    const float* b_off = (const float*)d_in[2];
    const float* w     = (const float*)d_in[3];
    float* out = (float*)d_out;

    float* om = (float*)d_ws;                                // 442368 f32
    unsigned short* x_t   = (unsigned short*)(om + 442368);  // 4*4096*256 bf16
    unsigned short* wprep = x_t + (size_t)4 * HWSZ * CIN;    // 589824 bf16
    unsigned short* woffp = wprep + 589824;                  // 73728 bf16

    hipLaunchKernelGGL(k_prep,     dim3(584), dim3(256), 0, stream, x, w, w_off, x_t, wprep, woffp);
    hipLaunchKernelGGL(k_off_mfma, dim3(512), dim3(256), 0, stream, x_t, woffp, b_off, om);
    hipLaunchKernelGGL(k_main,     dim3(256), dim3(512), 0, stream, x_t, om, wprep, out);
}

// Round 6
// 145.488 us; speedup vs baseline: 1.2395x; 1.2395x over previous
//
#include <hip/hip_runtime.h>
#include <math.h>

#define HH 64
#define WW 64
#define CIN 256
#define COUT 256
#define KKT 9
#define HWSZ 4096
#define VP 260                 // LDS row pitch in shorts

typedef __bf16  v8bf   __attribute__((ext_vector_type(8)));
typedef float   v4f    __attribute__((ext_vector_type(4)));
typedef short   short8 __attribute__((ext_vector_type(8)));
typedef unsigned short ushort4v __attribute__((ext_vector_type(4)));

__device__ inline unsigned short f2bf(float f) {   // RNE
    union { float f; unsigned u; } uf; uf.f = f;
    unsigned r = uf.u + 0x7fff + ((uf.u >> 16) & 1);
    return (unsigned short)(r >> 16);
}
__device__ inline float bf2f(unsigned short u) {
    union { unsigned u; float f; } uf; uf.u = ((unsigned)u) << 16;
    return uf.f;
}

// ---------------------------------------------------------------------------
// Merged prep kernel. Blocks 0..255: x -> x_t (channel-last bf16).
// Blocks 256..511: w -> wprep (LDS-staged, coalesced 16B writes).
// Blocks 512..583: w_off -> woffp.
// ---------------------------------------------------------------------------
__global__ __launch_bounds__(256) void k_prep(const float* __restrict__ x,
                                              const float* __restrict__ w,
                                              const float* __restrict__ w_off,
                                              unsigned short* __restrict__ x_t,
                                              unsigned short* __restrict__ wprep,
                                              unsigned short* __restrict__ woffp) {
    __shared__ float s_w[2304];
    int id  = blockIdx.x;
    int tid = threadIdx.x;
    if (id < 256) {
        int b  = id >> 6;
        int h  = id & 63;
        int px  = tid & 63;
        int oct = tid >> 6;
        const float* xr = x + (((size_t)b * CIN) * HH + h) * WW;
        unsigned short* orow = x_t + (((size_t)id) * WW + px) * CIN;
        for (int g = 0; g < 8; g++) {
            int cb = g * 32 + oct * 8;
            unsigned short v[8];
#pragma unroll
            for (int j = 0; j < 8; j++)
                v[j] = f2bf(xr[(size_t)(cb + j) * HWSZ + px]);
            *(short8*)(orow + cb) = *(short8*)v;
        }
    } else if (id < 512) {
        int o = id - 256;
        for (int i = tid; i < 2304; i += 256) s_w[i] = w[(size_t)o * 2304 + i];
        __syncthreads();
        for (int u = tid; u < 576; u += 256) {
            int t  = u >> 3;
            int kq = u & 7;
            unsigned short v[4];
#pragma unroll
            for (int j = 0; j < 4; j++) {
                int kp = t * 32 + kq * 4 + j;
                int kk = kp >> 8;
                int c  = kp & 255;
                v[j] = f2bf(s_w[c * 9 + kk]);
            }
            *(ushort4v*)&wprep[((size_t)(t * 256 + o)) * 32 + kq * 4] = *(ushort4v*)v;
        }
    } else {
        int t = id - 512;              // 0..71
#pragma unroll
        for (int i = 0; i < 4; i++) {
            int idx = i * 256 + tid;
            int och = idx >> 5;
            int ki  = idx & 31;
            int kp  = t * 32 + ki;
            int kk  = kp >> 8;
            int c   = kp & 255;
            float v = (och < 27) ? w_off[((size_t)och * 256 + c) * 9 + kk] : 0.f;
            woffp[(size_t)t * 1024 + idx] = f2bf(v);
        }
    }
}

// ---------------------------------------------------------------------------
// Offset conv MFMA. Grid 512: block = (b, h, px-half of 32). 256 thr, 4 waves.
// Stage 3 rows x 34 px once, K-chunks split over wave-pairs, LDS reduce.
// ---------------------------------------------------------------------------
__global__ __launch_bounds__(256) void k_off_mfma(const unsigned short* __restrict__ x_t,
                                                  const unsigned short* __restrict__ woffp,
                                                  const float* __restrict__ b_off,
                                                  float* __restrict__ om) {
    int id    = blockIdx.x;
    int g     = id & 7;
    int phalf = (id >> 3) & 1;
    int hi    = (id >> 4) & 7;
    int b     = id >> 7;
    int h     = g * 8 + hi;
    int p0    = phalf * 32;
    int tid  = threadIdx.x;
    int lane = tid & 63;
    int wv   = tid >> 6;               // 0..3
    int g2   = wv >> 1;                // K-split group
    int ntw  = wv & 1;                 // px 16-tile
    int m16  = lane & 15;
    int quad = lane >> 4;

    __shared__ unsigned short s_row[3 * 34 * VP];   // 53 KB
    __shared__ float s_red[2][32][33];

    const unsigned short* xb = x_t + (size_t)b * HWSZ * CIN;

    for (int u = tid; u < 3 * 1088; u += 256) {     // short8 units
        int row = u / 1088;
        int rem = u - row * 1088;
        int px  = rem >> 5;
        int c8  = (rem & 31) * 8;
        int y   = h + row - 1;
        int xg  = p0 + px - 1;
        short8 val = (short8)0;
        if ((unsigned)y < HH && (unsigned)xg < WW)
            val = *(const short8*)(xb + ((size_t)y * WW + xg) * CIN + c8);
        *(short8*)&s_row[(row * 34 + px) * VP + c8] = val;
    }
    __syncthreads();

    v4f acc[2];
    acc[0] = (v4f)(0.f);
    acc[1] = (v4f)(0.f);

#pragma unroll
    for (int ky = 0; ky < 3; ky++) {
#pragma unroll
        for (int kx = 0; kx < 3; kx++) {
#pragma unroll
            for (int c2 = 0; c2 < 4; c2++) {
                int ch = c2 * 2 + g2;
                int t  = (ky * 3 + kx) * 8 + ch;
                const unsigned short* wp = woffp + (size_t)t * 1024;
                short8 af0 = *(const short8*)(wp + m16 * 32 + quad * 8);
                short8 af1 = *(const short8*)(wp + (16 + m16) * 32 + quad * 8);
                short8 bfr = *(const short8*)
                    &s_row[(ky * 34 + ntw * 16 + m16 + kx) * VP + ch * 32 + quad * 8];
                acc[0] = __builtin_amdgcn_mfma_f32_16x16x32_bf16(
                    __builtin_bit_cast(v8bf, af0), __builtin_bit_cast(v8bf, bfr), acc[0], 0, 0, 0);
                acc[1] = __builtin_amdgcn_mfma_f32_16x16x32_bf16(
                    __builtin_bit_cast(v8bf, af1), __builtin_bit_cast(v8bf, bfr), acc[1], 0, 0, 0);
            }
        }
    }

#pragma unroll
    for (int mt = 0; mt < 2; mt++)
#pragma unroll
        for (int r = 0; r < 4; r++)
            s_red[g2][mt * 16 + quad * 4 + r][ntw * 16 + m16] = acc[mt][r];
    __syncthreads();

    for (int i2 = tid; i2 < 27 * 32; i2 += 256) {
        int och = i2 >> 5;
        int px  = i2 & 31;
        float s = s_red[0][och][px] + s_red[1][och][px] + b_off[och];
        om[((size_t)b * 27 + och) * HWSZ + h * WW + p0 + px] = s;
    }
}

// ---------------------------------------------------------------------------
// Main fused kernel — R4 structure, px-split for 2 blocks/CU.
// Grid 512 = (b, h, px-half). 512 thr (8 waves). Tile 256o x 32px.
// Wave oct: o in [oct*32, +32). Per kk: stage V_kk[32px][256ch] coalesced
// (lanes = channels), then 8 K-chunks of MFMA (2m x 2n each).
// ---------------------------------------------------------------------------
__global__ __launch_bounds__(512, 4) void k_main(const unsigned short* __restrict__ x_t,
                                                 const float* __restrict__ om,
                                                 const unsigned short* __restrict__ wprep,
                                                 float* __restrict__ out) {
    int id    = blockIdx.x;
    int g     = id & 7;
    int phalf = (id >> 3) & 1;
    int hi    = (id >> 4) & 7;
    int b     = id >> 7;
    int h     = g * 8 + hi;
    int p0    = phalf * 32;
    int tid  = threadIdx.x;
    int lane = tid & 63;
    int oct  = tid >> 6;               // wave 0..7: o in [oct*32, +32)
    int m16  = lane & 15;
    int quad = lane >> 4;

    __shared__ int4   s_base[KKT][32];
    __shared__ float4 s_wt  [KKT][32];
    __shared__ unsigned short s_v[32 * VP];

    // ---- Phase A: sampling params for 9 kk x 32 px ----
    const float* omb = om + (size_t)b * 27 * HWSZ + h * WW;
    for (int i = tid; i < KKT * 32; i += 512) {
        int kk = i >> 5;
        int pl = i & 31;
        int p  = p0 + pl;
        float offy = omb[(size_t)(2 * kk)     * HWSZ + p];
        float offx = omb[(size_t)(2 * kk + 1) * HWSZ + p];
        float mv   = omb[(size_t)(18 + kk)    * HWSZ + p];
        int ky = kk / 3, kx = kk - 3 * (kk / 3);
        float py = (float)(h - 1 + ky) + offy;
        float px = (float)(p - 1 + kx) + offx;
        float y0f = floorf(py);
        float x0f = floorf(px);
        float ly = py - y0f, lx = px - x0f;
        int y0 = (int)y0f, x0 = (int)x0f;
        float m = 1.f / (1.f + __expf(-mv));
        bool yv0 = (unsigned)y0       < HH;
        bool yv1 = (unsigned)(y0 + 1) < HH;
        bool xv0 = (unsigned)x0       < WW;
        bool xv1 = (unsigned)(x0 + 1) < WW;
        int y0c = min(max(y0, 0), HH - 1);
        int y1c = min(max(y0 + 1, 0), HH - 1);
        int x0c = min(max(x0, 0), WW - 1);
        int x1c = min(max(x0 + 1, 0), WW - 1);
        s_base[kk][pl] = make_int4((y0c * WW + x0c) * CIN, (y0c * WW + x1c) * CIN,
                                   (y1c * WW + x0c) * CIN, (y1c * WW + x1c) * CIN);
        s_wt[kk][pl] = make_float4(
            (yv0 && xv0) ? (1.f - ly) * (1.f - lx) * m : 0.f,
            (yv0 && xv1) ? (1.f - ly) * lx         * m : 0.f,
            (yv1 && xv0) ? ly * (1.f - lx)         * m : 0.f,
            (yv1 && xv1) ? ly * lx                 * m : 0.f);
    }
    __syncthreads();

    v4f acc[2][2];
#pragma unroll
    for (int mt = 0; mt < 2; mt++)
#pragma unroll
        for (int nt = 0; nt < 2; nt++) acc[mt][nt] = (v4f)(0.f);

    const unsigned short* xb = x_t + (size_t)b * HWSZ * CIN;
    const unsigned short* xc = xb + lane * 4;

    for (int kk = 0; kk < KKT; kk++) {
        // ---- stage V_kk: wave oct handles px_l = oct*4 .. +3; lanes=channels
#pragma unroll
        for (int i = 0; i < 4; i++) {
            int pl = oct * 4 + i;
            int4   bp = s_base[kk][pl];    // wave-uniform (LDS broadcast)
            float4 wt = s_wt[kk][pl];
            ushort4v t0 = *(const ushort4v*)(xc + bp.x);
            ushort4v t1 = *(const ushort4v*)(xc + bp.y);
            ushort4v t2 = *(const ushort4v*)(xc + bp.z);
            ushort4v t3 = *(const ushort4v*)(xc + bp.w);
            unsigned short vv[4];
#pragma unroll
            for (int j = 0; j < 4; j++) {
                float val = wt.x * bf2f(t0[j]) + wt.y * bf2f(t1[j])
                          + wt.z * bf2f(t2[j]) + wt.w * bf2f(t3[j]);
                vv[j] = f2bf(val);
            }
            *(ushort4v*)&s_v[pl * VP + lane * 4] = *(ushort4v*)vv;
        }
        __syncthreads();

        // ---- 8 K-chunks of MFMA for this kk ----
#pragma unroll 2
        for (int ch = 0; ch < 8; ch++) {
            int t = kk * 8 + ch;
            const unsigned short* wp = wprep + ((size_t)t * 256 + oct * 32) * 32;
            short8 af0 = *(const short8*)(wp + m16 * 32 + quad * 8);
            short8 af1 = *(const short8*)(wp + (16 + m16) * 32 + quad * 8);
            short8 bfr[2];
#pragma unroll
            for (int nt = 0; nt < 2; nt++)
                bfr[nt] = *(const short8*)&s_v[(nt * 16 + m16) * VP + ch * 32 + quad * 8];
#pragma unroll
            for (int nt = 0; nt < 2; nt++) {
                acc[0][nt] = __builtin_amdgcn_mfma_f32_16x16x32_bf16(
                    __builtin_bit_cast(v8bf, af0), __builtin_bit_cast(v8bf, bfr[nt]),
                    acc[0][nt], 0, 0, 0);
                acc[1][nt] = __builtin_amdgcn_mfma_f32_16x16x32_bf16(
                    __builtin_bit_cast(v8bf, af1), __builtin_bit_cast(v8bf, bfr[nt]),
                    acc[1][nt], 0, 0, 0);
            }
        }
        __syncthreads();
    }

    // ---- epilogue ----
    float* ob = out + ((size_t)b * COUT) * HWSZ + h * WW + p0;
#pragma unroll
    for (int mt = 0; mt < 2; mt++)
#pragma unroll
        for (int nt = 0; nt < 2; nt++)
#pragma unroll
            for (int r = 0; r < 4; r++) {
                int o = oct * 32 + mt * 16 + quad * 4 + r;
                ob[(size_t)o * HWSZ + nt * 16 + m16] = acc[mt][nt][r];
            }
}

extern "C" void kernel_launch(void* const* d_in, const int* in_sizes, int n_in,
                              void* d_out, int out_size, void* d_ws, size_t ws_size,
                              hipStream_t stream) {
    const float* x     = (const float*)d_in[0];
    const float* w_off = (const float*)d_in[1];
    const float* b_off = (const float*)d_in[2];
    const float* w     = (const float*)d_in[3];
    float* out = (float*)d_out;

    float* om = (float*)d_ws;                                // 442368 f32
    unsigned short* x_t   = (unsigned short*)(om + 442368);  // 4*4096*256 bf16
    unsigned short* wprep = x_t + (size_t)4 * HWSZ * CIN;    // 589824 bf16
    unsigned short* woffp = wprep + 589824;                  // 73728 bf16

    hipLaunchKernelGGL(k_prep,     dim3(584), dim3(256), 0, stream, x, w, w_off, x_t, wprep, woffp);
    hipLaunchKernelGGL(k_off_mfma, dim3(512), dim3(256), 0, stream, x_t, woffp, b_off, om);
    hipLaunchKernelGGL(k_main,     dim3(512), dim3(512), 0, stream, x_t, om, wprep, out);
}